// Round 22
// baseline (421.914 us; speedup 1.0000x reference)
//
#include <hip/hip_runtime.h>
#include <math.h>

#define D_DIM 128
#define H_DIM 256
#define W_DIM 256
#define HW (H_DIM * W_DIM)
#define HW4 (HW / 4)
#define NIMG 2
#define NPI (D_DIM * HW)
#define NTOT (NIMG * NPI)

#define TDZ 32
#define TH 16
#define TW 64

#define AW4R 18  // real aS chunks/row: chunk c -> gx = x0-4+4c (x0-4 .. x0+67)
#define AW4 19   // padded aS row stride
#define AH 20    // aS rows: gy = y0-2 .. y0+17
#define EW4R 17  // real eT chunks/row: chunk c -> gx = x0-2+4c (x0-2 .. x0+65)
#define EW4 19   // padded eT row stride
#define EH 18    // eT rows: gy = y0-1 .. y0+16

#define NLOADLIN (AH * AW4)   // 380 padded-linear load slots
#define NLOADP 384            // rounded to 6 full waves
#define NEPAIR ((EH / 2) * EW4R)  // 153 row-pair erode items

#define NUM_ITER 20
#define STOP_THRESH 1e-4

__device__ __forceinline__ float min3f(float a, float b, float c) { return fminf(fminf(a, b), c); }
__device__ __forceinline__ float max3f(float a, float b, float c) { return fmaxf(fmaxf(a, b), c); }
__device__ __forceinline__ float leaky(float x) { return fmaxf(x, 0.01f * x); }

__device__ __forceinline__ float4 f4max3v(float4 a, float4 b, float4 c) {
    float4 r;
    r.x = max3f(a.x, b.x, c.x); r.y = max3f(a.y, b.y, c.y);
    r.z = max3f(a.z, b.z, c.z); r.w = max3f(a.w, b.w, c.w);
    return r;
}

// lane L receives lane L+1's value within each 16-lane DPP row (row_shl:1).
__device__ __forceinline__ float dpp_shl1(float v) {
    int i = __float_as_int(v);
    int r = __builtin_amdgcn_update_dpp(i, i, 0x101, 0xF, 0xF, false);
    return __int_as_float(r);
}

#define BAR_FULL() do { asm volatile("s_waitcnt vmcnt(0) lgkmcnt(0)" ::: "memory"); \
                        __builtin_amdgcn_s_barrier(); \
                        __builtin_amdgcn_sched_barrier(0); } while (0)
#define BAR_VMN(N) do { asm volatile("s_waitcnt vmcnt(" #N ") lgkmcnt(0)" ::: "memory"); \
                        __builtin_amdgcn_s_barrier(); \
                        __builtin_amdgcn_sched_barrier(0); } while (0)
// B2: LDS-only drain — keeps global_load_lds for the next pair in flight
#define BAR_LDS() do { asm volatile("s_waitcnt lgkmcnt(0)" ::: "memory"); \
                       __builtin_amdgcn_s_barrier(); \
                       __builtin_amdgcn_sched_barrier(0); } while (0)

#define GLOAD_LDS(gp, lp) \
    __builtin_amdgcn_global_load_lds((const __attribute__((address_space(1))) unsigned int*)(gp), \
                                     (__attribute__((address_space(3))) unsigned int*)(lp), 16, 0, 0)

__global__ void init_slots(double* slots) {
    int t = threadIdx.x;
    if (t < 32) slots[t] = 0.0;
    if (t >= 32 && t < 36) ((float*)(slots + 32))[t - 32] = INFINITY;  // 16B +INF cell
}

// R21 + row-pair OUT phase: out item owns output rows (2rp, 2rp+1), reads
// 4 eT rows x 1 col (shared max(A1,A2)) = 2 reads/chunk vs 3; DPP for the
// neighbor column; boundary lanes (wq==15) read the 17th column directly.
// 128 items mapped to the LOWER HALF of every wave (oq = wv*32 + (ln&31)),
// so all 4 waves issue stores -> uniform vmcnt(8) accounting at B1.
__global__ __launch_bounds__(256) void skel_step(
    const float* __restrict__ a_in,
    float* __restrict__ a_out,
    float* __restrict__ skel,
    double* __restrict__ slots,
    int step)
{
    __shared__ float4 aS4[4][NLOADP];  // 24576 B (4 slice slots, gload dest)
    __shared__ float4 eT4[2][EH * EW4];// 10944 B (padded rows)
    __shared__ float wsum[4];

    const int t = threadIdx.x;

    // gating: uniform per-thread check
    {
        int act = 1;
        for (int j = 1; j < step; ++j)
            if (!(slots[j] >= STOP_THRESH * (double)NTOT)) { act = 0; break; }
        if (!act) return;
    }

    const float* infp = (const float*)(slots + 32);

    // XCD-aware swizzle: grid (4,16,8) = 512 blocks; XCD k owns swz in
    // [64k,64(k+1)).
    const int lid = blockIdx.x + 4 * (blockIdx.y + 16 * blockIdx.z);
    const int swz = (lid & 7) * 64 + (lid >> 3);
    const int bx = swz & 3;
    const int by = (swz >> 2) & 15;
    const int zz = swz >> 6;           // 0..7
    const int bz = zz & 3, img = zz >> 2;
    const int x0 = bx * TW, y0 = by * TH, z0 = bz * TDZ;

    const float* in = a_in + (size_t)img * NPI;
    float4* aout4 = (float4*)(a_out + (size_t)img * NPI);
    float4* sk4 = (float4*)(skel + (size_t)img * NPI);

    // ---- load items in PADDED-linear order: q0 = t, q1 = t+256 (t<128) ----
    int lOff0; bool lVal0;
    {
        int lr = t / AW4, lc = t - lr * AW4;
        int gy = y0 - 2 + lr, gx = x0 - 4 + 4 * lc;
        lVal0 = (lc < AW4R) && ((unsigned)gy < H_DIM) && ((unsigned)gx <= (unsigned)(W_DIM - 4));
        lOff0 = gy * W_DIM + gx;
    }
    const bool hasL1 = t < 128;          // wave-uniform
    int lOff1 = 0; bool lVal1 = false;
    if (hasL1) {
        int q = t + 256;
        int lr = q / AW4, lc = q - lr * AW4;
        int gy = y0 - 2 + lr, gx = x0 - 4 + 4 * lc;
        lVal1 = (q < NLOADLIN) && (lc < AW4R) && ((unsigned)gy < H_DIM)
                && ((unsigned)gx <= (unsigned)(W_DIM - 4));
        lOff1 = gy * W_DIM + gx;
    }
    const int wbase = (t >> 6) << 6;     // wave-uniform LDS base (element units)

    // ---- erode items: row-pair (rp, ej), t = rp*17 + ej, t < 153 ----
    const bool isE = t < NEPAIR;
    int eRdP = 0, eWrP = 0;
    bool s0A = false, s0B = false, s0C = false, s0D = false;
    bool s1A = false, s1B = false, s1C = false, s1D = false;
    if (isE) {
        int rp = t / EW4R, ej = t - rp * EW4R;
        int mh0 = 2 * rp;               // eT rows mh0, mh0+1
        eRdP = mh0 * AW4 + ej;          // aS rows mh0..mh0+3, cols ej, ej+1
        eWrP = mh0 * EW4 + ej;
        int gy0e = y0 - 1 + mh0;
        bool g0 = (unsigned)gy0e < H_DIM;
        bool g1 = (unsigned)(gy0e + 1) < H_DIM;
        int gxb = x0 - 2 + 4 * ej;
        bool xA = (unsigned)(gxb + 0) < W_DIM;
        bool xB = (unsigned)(gxb + 1) < W_DIM;
        bool xC = (unsigned)(gxb + 2) < W_DIM;
        bool xD = (unsigned)(gxb + 3) < W_DIM;
        s0A = g0 && xA; s0B = g0 && xB; s0C = g0 && xC; s0D = g0 && xD;
        s1A = g1 && xA; s1B = g1 && xB; s1C = g1 && xC; s1D = g1 && xD;
    }

    // ---- out items: row-pair, lower half of each wave ----
    const int wv = t >> 6, ln = t & 63;
    const bool isO = ln < 32;
    const int oq = (wv << 5) | (ln & 31);   // 0..127 when isO
    const int orp = oq >> 4;                // 0..7 (row pair)
    const int wq = oq & 15;
    const bool isB = (wq == 15);
    const int oRdP = (2 * orp) * EW4 + wq;  // eT rows 2orp..2orp+3
    const int oAc0 = (2 * orp + 2) * AW4 + wq + 1;
    const int oAc1 = oAc0 + AW4;
    size_t ob0 = ((size_t)z0 * HW + (size_t)(y0 + 2 * orp) * W_DIM + x0) / 4 + wq;
    size_t ob1 = ob0 + (W_DIM / 4);

    const float INF = INFINITY;
    const float4 ninf4 = make_float4(-INF, -INF, -INF, -INF);
    const float4 inf4 = make_float4(INF, INF, INF, INF);
    // erode D-chains
    float4 m0P2 = inf4, m0P1 = inf4, m1P2 = inf4, m1P1 = inf4;
    // out rolling state, per row of the pair
    float4 x0P2 = ninf4, x0P1 = ninf4, x1P2 = ninf4, x1P1 = ninf4;
    float4 ac0P2 = make_float4(0, 0, 0, 0), ac0P1 = ac0P2;
    float4 ac1P2 = ac0P2, ac1P1 = ac0P2;
    float4 ecP0 = ac0P2, ecP1 = ac0P2;
    float lsum = 0.f;

    // ---- prologue: issue slices 0,1 into slots 0,1 ----
    for (int s = 0; s < 2; ++s) {
        int z = z0 - 2 + s;
        bool zok = (unsigned)z < D_DIM;
        const float* p = in + (size_t)z * HW;
        const float* s0 = (zok && lVal0) ? (p + lOff0) : infp;
        GLOAD_LDS(s0, &aS4[s][wbase]);
        if (hasL1) {
            const float* s1 = (zok && lVal1) ? (p + lOff1) : infp;
            GLOAD_LDS(s1, &aS4[s][256 + wbase]);
        }
    }

    // Row-pair erode (unchanged from R20/R21)
    #define ERODE_SLICE(SLOT, ZPV, DO_E, ETI, P2_0, P1_0, P2_1, P1_1)              \
    do { if (isE) {                                                                \
        const float4* s_ = aS4[SLOT];                                              \
        float4 a0 = s_[eRdP],           b0 = s_[eRdP + 1];                         \
        float4 a1 = s_[eRdP + AW4],     b1 = s_[eRdP + AW4 + 1];                   \
        float4 a2 = s_[eRdP + 2 * AW4], b2 = s_[eRdP + 2 * AW4 + 1];               \
        float4 a3 = s_[eRdP + 3 * AW4], b3 = s_[eRdP + 3 * AW4 + 1];               \
        float4 ma;                                                                 \
        ma.x = fminf(a1.x, a2.x); ma.y = fminf(a1.y, a2.y);                        \
        ma.z = fminf(a1.z, a2.z); ma.w = fminf(a1.w, a2.w);                        \
        float4 v0a, v1a;                                                           \
        v0a.x = fminf(a0.x, ma.x); v0a.y = fminf(a0.y, ma.y);                      \
        v0a.z = fminf(a0.z, ma.z); v0a.w = fminf(a0.w, ma.w);                      \
        v1a.x = fminf(a3.x, ma.x); v1a.y = fminf(a3.y, ma.y);                      \
        v1a.z = fminf(a3.z, ma.z); v1a.w = fminf(a3.w, ma.w);                      \
        float mbx = fminf(b1.x, b2.x), mby = fminf(b1.y, b2.y), mbz = fminf(b1.z, b2.z); \
        float v0bx = fminf(b0.x, mbx), v0by = fminf(b0.y, mby), v0bz = fminf(b0.z, mbz); \
        float v1bx = fminf(b3.x, mbx), v1by = fminf(b3.y, mby), v1bz = fminf(b3.z, mbz); \
        float4 mC0, mC1;                                                           \
        mC0.x = min3f(v0a.y, v0a.z, v0a.w);                                        \
        mC0.y = min3f(v0a.z, v0a.w, v0bx);                                         \
        mC0.z = min3f(v0a.w, v0bx, v0by);                                          \
        mC0.w = min3f(v0bx, v0by, v0bz);                                           \
        mC1.x = min3f(v1a.y, v1a.z, v1a.w);                                        \
        mC1.y = min3f(v1a.z, v1a.w, v1bx);                                         \
        mC1.z = min3f(v1a.w, v1bx, v1by);                                          \
        mC1.w = min3f(v1bx, v1by, v1bz);                                           \
        if ((DO_E) && (ZPV)) {                                                     \
            float4 e;                                                              \
            e.x = s0A ? min3f(P2_0.x, P1_0.x, mC0.x) : -INF;                       \
            e.y = s0B ? min3f(P2_0.y, P1_0.y, mC0.y) : -INF;                       \
            e.z = s0C ? min3f(P2_0.z, P1_0.z, mC0.z) : -INF;                       \
            e.w = s0D ? min3f(P2_0.w, P1_0.w, mC0.w) : -INF;                       \
            eT4[ETI][eWrP] = e;                                                    \
            e.x = s1A ? min3f(P2_1.x, P1_1.x, mC1.x) : -INF;                       \
            e.y = s1B ? min3f(P2_1.y, P1_1.y, mC1.y) : -INF;                       \
            e.z = s1C ? min3f(P2_1.z, P1_1.z, mC1.z) : -INF;                       \
            e.w = s1D ? min3f(P2_1.w, P1_1.w, mC1.w) : -INF;                       \
            eT4[ETI][eWrP + EW4] = e;                                              \
        }                                                                          \
        P2_0 = P1_0; P1_0 = mC0; P2_1 = P1_1; P1_1 = mC1;                          \
    } } while (0)

    // Row-pair DPP dilation: 4 own-column reads -> 2 output rows. Shared
    // mm = max(A1,A2). Boundary lanes read the 17th column (4 chunks).
    #define MAX9P(ETI, xC0v, xC1v, ec0v, ec1v)                                     \
    do {                                                                           \
        const float4* eP_ = eT4[ETI];                                              \
        float4 A0 = eP_[oRdP],           A1 = eP_[oRdP + EW4];                     \
        float4 A2 = eP_[oRdP + 2 * EW4], A3 = eP_[oRdP + 3 * EW4];                 \
        float4 B0 = ninf4, B1 = ninf4, B2 = ninf4, B3 = ninf4;                     \
        if (isB) {                                                                 \
            B0 = eP_[oRdP + 1];           B1 = eP_[oRdP + EW4 + 1];                \
            B2 = eP_[oRdP + 2 * EW4 + 1]; B3 = eP_[oRdP + 3 * EW4 + 1];            \
        }                                                                          \
        float4 mm;                                                                 \
        mm.x = fmaxf(A1.x, A2.x); mm.y = fmaxf(A1.y, A2.y);                        \
        mm.z = fmaxf(A1.z, A2.z); mm.w = fmaxf(A1.w, A2.w);                        \
        float4 vm0, vm1;                                                           \
        vm0.x = fmaxf(A0.x, mm.x); vm0.y = fmaxf(A0.y, mm.y);                      \
        vm0.z = fmaxf(A0.z, mm.z); vm0.w = fmaxf(A0.w, mm.w);                      \
        vm1.x = fmaxf(A3.x, mm.x); vm1.y = fmaxf(A3.y, mm.y);                      \
        vm1.z = fmaxf(A3.z, mm.z); vm1.w = fmaxf(A3.w, mm.w);                      \
        float s0x = dpp_shl1(vm0.x), s0y = dpp_shl1(vm0.y), s0z = dpp_shl1(vm0.z); \
        float s1x = dpp_shl1(vm1.x), s1y = dpp_shl1(vm1.y), s1z = dpp_shl1(vm1.z); \
        float c1x = dpp_shl1(A1.x), c1y = dpp_shl1(A1.y);                          \
        float c2x = dpp_shl1(A2.x), c2y = dpp_shl1(A2.y);                          \
        float bv0x = max3f(B0.x, B1.x, B2.x);                                      \
        float bv0y = max3f(B0.y, B1.y, B2.y);                                      \
        float bv0z = max3f(B0.z, B1.z, B2.z);                                      \
        float bv1x = max3f(B1.x, B2.x, B3.x);                                      \
        float bv1y = max3f(B1.y, B2.y, B3.y);                                      \
        float bv1z = max3f(B1.z, B2.z, B3.z);                                      \
        float n0x = isB ? bv0x : s0x, n0y = isB ? bv0y : s0y, n0z = isB ? bv0z : s0z; \
        float n1x = isB ? bv1x : s1x, n1y = isB ? bv1y : s1y, n1z = isB ? bv1z : s1z; \
        xC0v.x = max3f(vm0.y, vm0.z, vm0.w);                                       \
        xC0v.y = max3f(vm0.z, vm0.w, n0x);                                         \
        xC0v.z = max3f(vm0.w, n0x, n0y);                                           \
        xC0v.w = max3f(n0x, n0y, n0z);                                             \
        xC1v.x = max3f(vm1.y, vm1.z, vm1.w);                                       \
        xC1v.y = max3f(vm1.z, vm1.w, n1x);                                         \
        xC1v.z = max3f(vm1.w, n1x, n1y);                                           \
        xC1v.w = max3f(n1x, n1y, n1z);                                             \
        ec0v.x = A1.z; ec0v.y = A1.w;                                              \
        ec0v.z = isB ? B1.x : c1x; ec0v.w = isB ? B1.y : c1y;                      \
        ec1v.x = A2.z; ec1v.y = A2.w;                                              \
        ec1v.z = isB ? B2.x : c2x; ec1v.w = isB ? B2.y : c2y;                      \
    } while (0)

    // one output (row, slice): dilation-max + leaky + skel update
    #define OUT1(OB, GG, ACv, XA, XB, XC, ECW)                                     \
    do {                                                                           \
        float4 dm = f4max3v(XA, XB, XC);                                           \
        float4 dl;                                                                 \
        dl.x = leaky(ACv.x - dm.x); dl.y = leaky(ACv.y - dm.y);                    \
        dl.z = leaky(ACv.z - dm.z); dl.w = leaky(ACv.w - dm.w);                    \
        if (step < NUM_ITER) aout4[OB] = ECW;                                      \
        if (step == 0) {                                                           \
            sk4[OB] = dl;                                                          \
        } else {                                                                   \
            float4 gg = GG, up, gn;                                                \
            up.x = leaky(dl.x - gg.x * dl.x); gn.x = gg.x + up.x;                  \
            up.y = leaky(dl.y - gg.y * dl.y); gn.y = gg.y + up.y;                  \
            up.z = leaky(dl.z - gg.z * dl.z); gn.z = gg.z + up.z;                  \
            up.w = leaky(dl.w - gg.w * dl.w); gn.w = gg.w + up.w;                  \
            sk4[OB] = gn;                                                          \
            if (step == 1)                                                         \
                lsum += fabsf(gn.x) + fabsf(gn.y) + fabsf(gn.z) + fabsf(gn.w);     \
            else                                                                   \
                lsum += fabsf(up.x) + fabsf(up.y) + fabsf(up.z) + fabsf(up.w);     \
        }                                                                          \
    } while (0)

    for (int k = 0; k < (TDZ + 4) / 2; ++k) {
        const int i0 = 2 * k, i1 = 2 * k + 1;
        const int slot0 = i0 & 3, slot1 = i1 & 3;

        // B1: pair slices loaded. k<3: full drain. k>=3: leave prior pair's
        // stores in flight (8 per wave; 4 at step 20) -> counted vmcnt.
        if (k < 3) { BAR_FULL(); }
        else if (step == NUM_ITER) { BAR_VMN(4); }
        else { BAR_VMN(8); }

        // early skel prefetch (oldest VMEM of the pair; 4 per out item)
        float4 ggP00, ggP01, ggP10, ggP11;
        if (step > 0 && i0 >= 4 && isO) {
            ggP00 = sk4[ob0]; ggP01 = sk4[ob0 + HW4];
            ggP10 = sk4[ob1]; ggP11 = sk4[ob1 + HW4];
        }
        __builtin_amdgcn_sched_barrier(0);

        // issue next pair (slices 2k+2, 2k+3) into the opposite slots
        if (k <= (TDZ + 4) / 2 - 2) {
            for (int s = 0; s < 2; ++s) {
                int z = z0 + 2 * k + s;
                bool zok = (unsigned)z < D_DIM;
                const float* p = in + (size_t)z * HW;
                const float* s0 = (zok && lVal0) ? (p + lOff0) : infp;
                GLOAD_LDS(s0, &aS4[(i0 + 2 + s) & 3][wbase]);
                if (hasL1) {
                    const float* s1 = (zok && lVal1) ? (p + lOff1) : infp;
                    GLOAD_LDS(s1, &aS4[(i0 + 2 + s) & 3][256 + wbase]);
                }
            }
        }
        __builtin_amdgcn_sched_barrier(0);

        const bool zp0 = (unsigned)(z0 - 3 + i0) < D_DIM;
        const bool zp1 = (unsigned)(z0 - 3 + i1) < D_DIM;
        const bool doE = (i0 >= 2);

        // ---- erode both slices -> eT4[0], eT4[1] ----
        ERODE_SLICE(slot0, zp0, doE, 0, m0P2, m0P1, m1P2, m1P1);
        ERODE_SLICE(slot1, zp1, (i1 >= 2), 1, m0P2, m0P1, m1P2, m1P1);

        // a-centers for both slices & rows (pre-B2; aS4 pair stable)
        float4 aA0, aA1, aB0, aB1;
        if (isO) {
            aA0 = aS4[slot0][oAc0]; aA1 = aS4[slot0][oAc1];
            aB0 = aS4[slot1][oAc0]; aB1 = aS4[slot1][oAc1];
        }

        BAR_LDS();  // B2: eT4 ready (vmcnt NOT drained — next pair in flight)

        // ---- out: both slices x both rows ----
        if (isO) {
            float4 xCA0, xCA1, ecA0, ecA1, xCB0, xCB1, ecB0, ecB1;
            if (doE && zp0) { MAX9P(0, xCA0, xCA1, ecA0, ecA1); }
            else { xCA0 = ninf4; xCA1 = ninf4; ecA0 = ninf4; ecA1 = ninf4; }
            if (doE && zp1) { MAX9P(1, xCB0, xCB1, ecB0, ecB1); }
            else { xCB0 = ninf4; xCB1 = ninf4; ecB0 = ninf4; ecB1 = ninf4; }

            if (i0 >= 4) {
                OUT1(ob0,       ggP00, ac0P2, x0P2, x0P1, xCA0, ecP0);
                OUT1(ob0 + HW4, ggP01, ac0P1, x0P1, xCA0, xCB0, ecA0);
                OUT1(ob1,       ggP10, ac1P2, x1P2, x1P1, xCA1, ecP1);
                OUT1(ob1 + HW4, ggP11, ac1P1, x1P1, xCA1, xCB1, ecA1);
                ob0 += 2 * HW4; ob1 += 2 * HW4;
            }
            x0P2 = xCA0; x0P1 = xCB0; x1P2 = xCA1; x1P1 = xCB1;
            ac0P2 = aA0; ac0P1 = aB0; ac1P2 = aA1; ac1P1 = aB1;
            ecP0 = ecB0; ecP1 = ecB1;
        }
    }

    #undef ERODE_SLICE
    #undef MAX9P
    #undef OUT1

    // dn reduction: one double atomic per block
    if (step > 0) {
        #pragma unroll
        for (int off = 32; off > 0; off >>= 1)
            lsum += __shfl_down(lsum, off, 64);
        const int lane = t & 63, wid = t >> 6;
        if (lane == 0) wsum[wid] = lsum;
        __syncthreads();
        if (t == 0) {
            float b = wsum[0] + wsum[1] + wsum[2] + wsum[3];
            atomicAdd(&slots[step], (double)b);
        }
    }
}

extern "C" void kernel_launch(void* const* d_in, const int* in_sizes, int n_in,
                              void* d_out, int out_size, void* d_ws, size_t ws_size,
                              hipStream_t stream) {
    const float* img = (const float*)d_in[0];
    float* out = (float*)d_out;
    float* buf0 = (float*)d_ws;
    float* buf1 = buf0 + NTOT;
    double* slots = (double*)(buf1 + NTOT);

    init_slots<<<1, 64, 0, stream>>>(slots);

    dim3 grid(W_DIM / TW, H_DIM / TH, (D_DIM / TDZ) * NIMG);
    for (int s = 0; s <= NUM_ITER; ++s) {
        const float* ain = (s == 0) ? img : ((s & 1) ? buf0 : buf1);
        float* aout = (s & 1) ? buf1 : buf0;
        skel_step<<<grid, 256, 0, stream>>>(ain, aout, out, slots, s);
    }
}

// Round 23
// 325.035 us; speedup vs baseline: 1.2981x; 1.2981x over previous
//
#include <hip/hip_runtime.h>
#include <math.h>

#define D_DIM 128
#define H_DIM 256
#define W_DIM 256
#define HW (H_DIM * W_DIM)
#define HW4 (HW / 4)
#define NIMG 2
#define NPI (D_DIM * HW)
#define NTOT (NIMG * NPI)

#define TDZ 32
#define TH 16
#define TW 64

#define AW4R 18  // real aS chunks/row: chunk c -> gx = x0-4+4c (x0-4 .. x0+67)
#define AW4 19   // padded aS row stride
#define AH 20    // aS rows: gy = y0-2 .. y0+17
#define EW4R 17  // real eT chunks/row: chunk c -> gx = x0-2+4c (x0-2 .. x0+65)
#define EW4 19   // padded eT row stride
#define EH 18    // eT rows: gy = y0-1 .. y0+16

#define NLOADLIN (AH * AW4)   // 380 padded-linear load slots
#define NLOADP 384            // rounded to 6 full waves
#define NEPAIR ((EH / 2) * EW4R)  // 153 row-pair erode items

#define NUM_ITER 20
#define STOP_THRESH 1e-4

__device__ __forceinline__ float min3f(float a, float b, float c) { return fminf(fminf(a, b), c); }
__device__ __forceinline__ float max3f(float a, float b, float c) { return fmaxf(fmaxf(a, b), c); }
__device__ __forceinline__ float leaky(float x) { return fmaxf(x, 0.01f * x); }

// lane L receives lane L+1's value within each 16-lane DPP row (row_shl:1).
// Must be executed by ALL lanes (uniform control flow) so source data exists.
__device__ __forceinline__ float dpp_shl1(float v) {
    int i = __float_as_int(v);
    int r = __builtin_amdgcn_update_dpp(i, i, 0x101, 0xF, 0xF, false);
    return __int_as_float(r);
}

// B1 variants: drain gloads but leave prior-pair stores in flight where safe.
#define BAR_FULL() do { asm volatile("s_waitcnt vmcnt(0) lgkmcnt(0)" ::: "memory"); \
                        __builtin_amdgcn_s_barrier(); \
                        __builtin_amdgcn_sched_barrier(0); } while (0)
#define BAR_VM4()  do { asm volatile("s_waitcnt vmcnt(4) lgkmcnt(0)" ::: "memory"); \
                        __builtin_amdgcn_s_barrier(); \
                        __builtin_amdgcn_sched_barrier(0); } while (0)
#define BAR_VM2()  do { asm volatile("s_waitcnt vmcnt(2) lgkmcnt(0)" ::: "memory"); \
                        __builtin_amdgcn_s_barrier(); \
                        __builtin_amdgcn_sched_barrier(0); } while (0)
// B2: LDS-only drain — keeps global_load_lds for the next pair in flight
#define BAR_LDS() do { asm volatile("s_waitcnt lgkmcnt(0)" ::: "memory"); \
                       __builtin_amdgcn_s_barrier(); \
                       __builtin_amdgcn_sched_barrier(0); } while (0)

#define GLOAD_LDS(gp, lp) \
    __builtin_amdgcn_global_load_lds((const __attribute__((address_space(1))) unsigned int*)(gp), \
                                     (__attribute__((address_space(3))) unsigned int*)(lp), 16, 0, 0)

__global__ void init_slots(double* slots) {
    int t = threadIdx.x;
    if (t < 32) slots[t] = 0.0;
    if (t >= 32 && t < 36) ((float*)(slots + 32))[t - 32] = INFINITY;  // 16B +INF cell
}

// R20 structure (row-pair erode + DPP dilation), TDZ 16->32: 36 iterations per
// 32 outputs (fill amortization 1.125x vs 1.25x), grid 512 blocks = 2/CU.
__global__ __launch_bounds__(256) void skel_step(
    const float* __restrict__ a_in,
    float* __restrict__ a_out,
    float* __restrict__ skel,
    double* __restrict__ slots,
    int step)
{
    __shared__ float4 aS4[4][NLOADP];  // 24576 B (4 slice slots, gload dest)
    __shared__ float4 eT4[2][EH * EW4];// 10944 B (padded rows)
    __shared__ float wsum[4];

    const int t = threadIdx.x;

    // gating: uniform per-thread check (slots[] reads are scalar/L2-cached)
    {
        int act = 1;
        for (int j = 1; j < step; ++j)
            if (!(slots[j] >= STOP_THRESH * (double)NTOT)) { act = 0; break; }
        if (!act) return;
    }

    const float* infp = (const float*)(slots + 32);

    // XCD-aware swizzle: grid (4,16,8) = 512 blocks; XCD k owns swz in
    // [64k,64(k+1)) = full xy coverage of 1 z-slab.
    const int lid = blockIdx.x + 4 * (blockIdx.y + 16 * blockIdx.z);
    const int swz = (lid & 7) * 64 + (lid >> 3);
    const int bx = swz & 3;
    const int by = (swz >> 2) & 15;
    const int zz = swz >> 6;           // 0..7
    const int bz = zz & 3, img = zz >> 2;
    const int x0 = bx * TW, y0 = by * TH, z0 = bz * TDZ;

    const float* in = a_in + (size_t)img * NPI;
    float4* aout4 = (float4*)(a_out + (size_t)img * NPI);
    float4* sk4 = (float4*)(skel + (size_t)img * NPI);

    // ---- load items in PADDED-linear order: q0 = t, q1 = t+256 (t<128) ----
    int lOff0; bool lVal0;
    {
        int lr = t / AW4, lc = t - lr * AW4;
        int gy = y0 - 2 + lr, gx = x0 - 4 + 4 * lc;
        lVal0 = (lc < AW4R) && ((unsigned)gy < H_DIM) && ((unsigned)gx <= (unsigned)(W_DIM - 4));
        lOff0 = gy * W_DIM + gx;
    }
    const bool hasL1 = t < 128;          // wave-uniform
    int lOff1 = 0; bool lVal1 = false;
    if (hasL1) {
        int q = t + 256;
        int lr = q / AW4, lc = q - lr * AW4;
        int gy = y0 - 2 + lr, gx = x0 - 4 + 4 * lc;
        lVal1 = (q < NLOADLIN) && (lc < AW4R) && ((unsigned)gy < H_DIM)
                && ((unsigned)gx <= (unsigned)(W_DIM - 4));
        lOff1 = gy * W_DIM + gx;
    }
    const int wbase = (t >> 6) << 6;     // wave-uniform LDS base (element units)

    // ---- erode items: row-pair (rp, ej), t = rp*17 + ej, t < 153 ----
    const bool isE = t < NEPAIR;
    int eRdP = 0, eWrP = 0;
    bool s0A = false, s0B = false, s0C = false, s0D = false;
    bool s1A = false, s1B = false, s1C = false, s1D = false;
    if (isE) {
        int rp = t / EW4R, ej = t - rp * EW4R;
        int mh0 = 2 * rp;               // eT rows mh0, mh0+1
        eRdP = mh0 * AW4 + ej;          // aS rows mh0..mh0+3, cols ej, ej+1
        eWrP = mh0 * EW4 + ej;
        int gy0e = y0 - 1 + mh0;
        bool g0 = (unsigned)gy0e < H_DIM;
        bool g1 = (unsigned)(gy0e + 1) < H_DIM;
        int gxb = x0 - 2 + 4 * ej;
        bool xA = (unsigned)(gxb + 0) < W_DIM;
        bool xB = (unsigned)(gxb + 1) < W_DIM;
        bool xC = (unsigned)(gxb + 2) < W_DIM;
        bool xD = (unsigned)(gxb + 3) < W_DIM;
        s0A = g0 && xA; s0B = g0 && xB; s0C = g0 && xC; s0D = g0 && xD;
        s1A = g1 && xA; s1B = g1 && xB; s1C = g1 && xC; s1D = g1 && xD;
    }

    // ---- out item ----
    const int oh = t >> 4, wq = t & 15;
    const bool isB = (wq == 15);         // boundary lane: owns the 17th column
    const int oRd = oh * EW4 + wq;
    const int oAc = (oh + 2) * AW4 + wq + 1;
    size_t ob = ((size_t)z0 * HW + (size_t)(y0 + oh) * W_DIM + (size_t)x0) / 4 + wq;

    const float INF = INFINITY;
    const float4 ninf4 = make_float4(-INF, -INF, -INF, -INF);
    const float4 inf4 = make_float4(INF, INF, INF, INF);
    // rolling D-chains: row0 (m0*) and row1 (m1*) of the pair; advance per slice
    float4 m0P2 = inf4, m0P1 = inf4, m1P2 = inf4, m1P1 = inf4;
    float4 xP2 = ninf4, xP1 = ninf4;
    float4 acP2 = make_float4(0, 0, 0, 0), acP1 = acP2, ecP = acP2;
    float lsum = 0.f;

    // ---- prologue: issue slices 0,1 into slots 0,1 ----
    for (int s = 0; s < 2; ++s) {
        int z = z0 - 2 + s;
        bool zok = (unsigned)z < D_DIM;
        const float* p = in + (size_t)z * HW;
        const float* s0 = (zok && lVal0) ? (p + lOff0) : infp;
        GLOAD_LDS(s0, &aS4[s][wbase]);
        if (hasL1) {
            const float* s1 = (zok && lVal1) ? (p + lOff1) : infp;
            GLOAD_LDS(s1, &aS4[s][256 + wbase]);
        }
    }

    // Row-pair erode: 4 rows x 2 cols = 8 b128 -> 2 output chunks. Vertical
    // windows share min(a1,a2). P2_0/P1_0 = row0 D-chain, P2_1/P1_1 = row1.
    #define ERODE_SLICE(SLOT, ZPV, DO_E, ETI, P2_0, P1_0, P2_1, P1_1)              \
    do { if (isE) {                                                                \
        const float4* s_ = aS4[SLOT];                                              \
        float4 a0 = s_[eRdP],           b0 = s_[eRdP + 1];                         \
        float4 a1 = s_[eRdP + AW4],     b1 = s_[eRdP + AW4 + 1];                   \
        float4 a2 = s_[eRdP + 2 * AW4], b2 = s_[eRdP + 2 * AW4 + 1];               \
        float4 a3 = s_[eRdP + 3 * AW4], b3 = s_[eRdP + 3 * AW4 + 1];               \
        float4 ma;                                                                 \
        ma.x = fminf(a1.x, a2.x); ma.y = fminf(a1.y, a2.y);                        \
        ma.z = fminf(a1.z, a2.z); ma.w = fminf(a1.w, a2.w);                        \
        float4 v0a, v1a;                                                           \
        v0a.x = fminf(a0.x, ma.x); v0a.y = fminf(a0.y, ma.y);                      \
        v0a.z = fminf(a0.z, ma.z); v0a.w = fminf(a0.w, ma.w);                      \
        v1a.x = fminf(a3.x, ma.x); v1a.y = fminf(a3.y, ma.y);                      \
        v1a.z = fminf(a3.z, ma.z); v1a.w = fminf(a3.w, ma.w);                      \
        float mbx = fminf(b1.x, b2.x), mby = fminf(b1.y, b2.y), mbz = fminf(b1.z, b2.z); \
        float v0bx = fminf(b0.x, mbx), v0by = fminf(b0.y, mby), v0bz = fminf(b0.z, mbz); \
        float v1bx = fminf(b3.x, mbx), v1by = fminf(b3.y, mby), v1bz = fminf(b3.z, mbz); \
        float4 mC0, mC1;                                                           \
        mC0.x = min3f(v0a.y, v0a.z, v0a.w);                                        \
        mC0.y = min3f(v0a.z, v0a.w, v0bx);                                         \
        mC0.z = min3f(v0a.w, v0bx, v0by);                                          \
        mC0.w = min3f(v0bx, v0by, v0bz);                                           \
        mC1.x = min3f(v1a.y, v1a.z, v1a.w);                                        \
        mC1.y = min3f(v1a.z, v1a.w, v1bx);                                         \
        mC1.z = min3f(v1a.w, v1bx, v1by);                                          \
        mC1.w = min3f(v1bx, v1by, v1bz);                                           \
        if ((DO_E) && (ZPV)) {                                                     \
            float4 e;                                                              \
            e.x = s0A ? min3f(P2_0.x, P1_0.x, mC0.x) : -INF;                       \
            e.y = s0B ? min3f(P2_0.y, P1_0.y, mC0.y) : -INF;                       \
            e.z = s0C ? min3f(P2_0.z, P1_0.z, mC0.z) : -INF;                       \
            e.w = s0D ? min3f(P2_0.w, P1_0.w, mC0.w) : -INF;                       \
            eT4[ETI][eWrP] = e;                                                    \
            e.x = s1A ? min3f(P2_1.x, P1_1.x, mC1.x) : -INF;                       \
            e.y = s1B ? min3f(P2_1.y, P1_1.y, mC1.y) : -INF;                       \
            e.z = s1C ? min3f(P2_1.z, P1_1.z, mC1.z) : -INF;                       \
            e.w = s1D ? min3f(P2_1.w, P1_1.w, mC1.w) : -INF;                       \
            eT4[ETI][eWrP + EW4] = e;                                              \
        }                                                                          \
        P2_0 = P1_0; P1_0 = mC0; P2_1 = P1_1; P1_1 = mC1;                          \
    } } while (0)

    // DPP dilation: 3 own-column reads + divergent 17th-column reads on wq==15;
    // neighbor column's vertical max + raw center row via row_shl:1 DPP.
    // NOTE: dpp_shl1 must run in uniform control flow (all 256 lanes).
    #define MAX9(ETI, xCv, ecv)                                                    \
    do {                                                                           \
        const float4* eP_ = eT4[ETI];                                              \
        float4 A0 = eP_[oRd], A1 = eP_[oRd + EW4], A2 = eP_[oRd + 2 * EW4];        \
        float4 B0, B1, B2;                                                         \
        if (isB) {                                                                 \
            B0 = eP_[oRd + 1]; B1 = eP_[oRd + EW4 + 1]; B2 = eP_[oRd + 2 * EW4 + 1]; \
        }                                                                          \
        float4 vm;                                                                 \
        vm.x = max3f(A0.x, A1.x, A2.x); vm.y = max3f(A0.y, A1.y, A2.y);            \
        vm.z = max3f(A0.z, A1.z, A2.z); vm.w = max3f(A0.w, A1.w, A2.w);            \
        float sx = dpp_shl1(vm.x), sy = dpp_shl1(vm.y), sz = dpp_shl1(vm.z);       \
        float c1x = dpp_shl1(A1.x), c1y = dpp_shl1(A1.y);                          \
        float bvx = max3f(B0.x, B1.x, B2.x);                                       \
        float bvy = max3f(B0.y, B1.y, B2.y);                                       \
        float bvz = max3f(B0.z, B1.z, B2.z);                                       \
        float nbx = isB ? bvx : sx;                                                \
        float nby = isB ? bvy : sy;                                                \
        float nbz = isB ? bvz : sz;                                                \
        xCv.x = max3f(vm.y, vm.z, vm.w);                                           \
        xCv.y = max3f(vm.z, vm.w, nbx);                                            \
        xCv.z = max3f(vm.w, nbx, nby);                                             \
        xCv.w = max3f(nbx, nby, nbz);                                              \
        ecv.x = A1.z; ecv.y = A1.w;                                                \
        ecv.z = isB ? B1.x : c1x;                                                  \
        ecv.w = isB ? B1.y : c1y;                                                  \
    } while (0)

    for (int k = 0; k < (TDZ + 4) / 2; ++k) {
        const int i0 = 2 * k, i1 = 2 * k + 1;
        const int slot0 = i0 & 3, slot1 = i1 & 3;

        // B1: pair slices loaded. k<3: only gloads outstanding -> full drain.
        // k>=3: leave prior pair's stores (4; 2 at step 20) in flight.
        if (k < 3) { BAR_FULL(); }
        else if (step == NUM_ITER) { BAR_VM2(); }
        else { BAR_VM4(); }

        // early skel prefetch (oldest VMEM of the pair)
        float4 ggPre0, ggPre1;
        if (step > 0 && i0 >= 4) { ggPre0 = sk4[ob]; ggPre1 = sk4[ob + HW4]; }
        __builtin_amdgcn_sched_barrier(0);

        // issue next pair (slices 2k+2, 2k+3) into the opposite slots
        if (k <= (TDZ + 4) / 2 - 2) {
            for (int s = 0; s < 2; ++s) {
                int z = z0 + 2 * k + s;          // slice 2k+2+s -> z0-2+(2k+2+s)
                bool zok = (unsigned)z < D_DIM;
                const float* p = in + (size_t)z * HW;
                const float* s0 = (zok && lVal0) ? (p + lOff0) : infp;
                GLOAD_LDS(s0, &aS4[(i0 + 2 + s) & 3][wbase]);
                if (hasL1) {
                    const float* s1 = (zok && lVal1) ? (p + lOff1) : infp;
                    GLOAD_LDS(s1, &aS4[(i0 + 2 + s) & 3][256 + wbase]);
                }
            }
        }
        __builtin_amdgcn_sched_barrier(0);

        const bool zp0 = (unsigned)(z0 - 3 + i0) < D_DIM;
        const bool zp1 = (unsigned)(z0 - 3 + i1) < D_DIM;
        const bool doE = (i0 >= 2);

        // ---- erode both slices -> eT4[0], eT4[1] ----
        ERODE_SLICE(slot0, zp0, doE, 0, m0P2, m0P1, m1P2, m1P1);
        ERODE_SLICE(slot1, zp1, (i1 >= 2), 1, m0P2, m0P1, m1P2, m1P1);

        // a-centers for both slices (issued pre-B2; aS4 pair stable)
        const float4 aCn0 = aS4[slot0][oAc];
        const float4 aCn1 = aS4[slot1][oAc];

        BAR_LDS();  // B2: eT4 ready (vmcnt NOT drained — next pair in flight)

        // ---- out both slices ----
        {
            float4 xC0, ecB0, xC1, ecB1;
            if (doE && zp0) { MAX9(0, xC0, ecB0); } else { xC0 = ninf4; ecB0 = ninf4; }
            if (doE && zp1) { MAX9(1, xC1, ecB1); } else { xC1 = ninf4; ecB1 = ninf4; }

            if (i0 >= 4) {
                {
                    float4 dl;
                    dl.x = leaky(acP2.x - max3f(xP2.x, xP1.x, xC0.x));
                    dl.y = leaky(acP2.y - max3f(xP2.y, xP1.y, xC0.y));
                    dl.z = leaky(acP2.z - max3f(xP2.z, xP1.z, xC0.z));
                    dl.w = leaky(acP2.w - max3f(xP2.w, xP1.w, xC0.w));
                    if (step < NUM_ITER) aout4[ob] = ecP;
                    if (step == 0) {
                        sk4[ob] = dl;
                    } else {
                        float4 gg = ggPre0, up, gn;
                        up.x = leaky(dl.x - gg.x * dl.x); gn.x = gg.x + up.x;
                        up.y = leaky(dl.y - gg.y * dl.y); gn.y = gg.y + up.y;
                        up.z = leaky(dl.z - gg.z * dl.z); gn.z = gg.z + up.z;
                        up.w = leaky(dl.w - gg.w * dl.w); gn.w = gg.w + up.w;
                        sk4[ob] = gn;
                        if (step == 1)
                            lsum += fabsf(gn.x) + fabsf(gn.y) + fabsf(gn.z) + fabsf(gn.w);
                        else
                            lsum += fabsf(up.x) + fabsf(up.y) + fabsf(up.z) + fabsf(up.w);
                    }
                }
                {
                    float4 dl;
                    dl.x = leaky(acP1.x - max3f(xP1.x, xC0.x, xC1.x));
                    dl.y = leaky(acP1.y - max3f(xP1.y, xC0.y, xC1.y));
                    dl.z = leaky(acP1.z - max3f(xP1.z, xC0.z, xC1.z));
                    dl.w = leaky(acP1.w - max3f(xP1.w, xC0.w, xC1.w));
                    if (step < NUM_ITER) aout4[ob + HW4] = ecB0;
                    if (step == 0) {
                        sk4[ob + HW4] = dl;
                    } else {
                        float4 gg = ggPre1, up, gn;
                        up.x = leaky(dl.x - gg.x * dl.x); gn.x = gg.x + up.x;
                        up.y = leaky(dl.y - gg.y * dl.y); gn.y = gg.y + up.y;
                        up.z = leaky(dl.z - gg.z * dl.z); gn.z = gg.z + up.z;
                        up.w = leaky(dl.w - gg.w * dl.w); gn.w = gg.w + up.w;
                        sk4[ob + HW4] = gn;
                        if (step == 1)
                            lsum += fabsf(gn.x) + fabsf(gn.y) + fabsf(gn.z) + fabsf(gn.w);
                        else
                            lsum += fabsf(up.x) + fabsf(up.y) + fabsf(up.z) + fabsf(up.w);
                    }
                }
                ob += 2 * HW4;
            }
            xP2 = xC0; xP1 = xC1;
            acP2 = aCn0; acP1 = aCn1;
            ecP = ecB1;
        }
    }

    #undef ERODE_SLICE
    #undef MAX9

    // dn reduction: one double atomic per block
    if (step > 0) {
        #pragma unroll
        for (int off = 32; off > 0; off >>= 1)
            lsum += __shfl_down(lsum, off, 64);
        const int lane = t & 63, wid = t >> 6;
        if (lane == 0) wsum[wid] = lsum;
        __syncthreads();
        if (t == 0) {
            float b = wsum[0] + wsum[1] + wsum[2] + wsum[3];
            atomicAdd(&slots[step], (double)b);
        }
    }
}

extern "C" void kernel_launch(void* const* d_in, const int* in_sizes, int n_in,
                              void* d_out, int out_size, void* d_ws, size_t ws_size,
                              hipStream_t stream) {
    const float* img = (const float*)d_in[0];
    float* out = (float*)d_out;
    float* buf0 = (float*)d_ws;
    float* buf1 = buf0 + NTOT;
    double* slots = (double*)(buf1 + NTOT);

    init_slots<<<1, 64, 0, stream>>>(slots);

    dim3 grid(W_DIM / TW, H_DIM / TH, (D_DIM / TDZ) * NIMG);
    for (int s = 0; s <= NUM_ITER; ++s) {
        const float* ain = (s == 0) ? img : ((s & 1) ? buf0 : buf1);
        float* aout = (s & 1) ? buf1 : buf0;
        skel_step<<<grid, 256, 0, stream>>>(ain, aout, out, slots, s);
    }
}